// Round 9
// baseline (41.850 us; speedup 1.0000x reference)
//
#include <hip/hip_runtime.h>

// Clustering layer: q[n,k] = t-dist kernel of ||z_n - c_k||^2, row-normalized.
// N=131072, K=100 (pad->112), D=256. f32 in/out; f16 MFMA for the dot products.
//
// R8: prefetch distance 2. K-loop fully unrolled with a ring of 3 named load
//     sets (static idx -> regs). At consume(s), loads(s+1)+loads(s+2) in
//     flight = ~16KB/wave outstanding vs ~900cyc HBM latency. R7 post-mortem:
//     depth-1 gives only ~800cyc cover at 4 waves/SIMD -- marginal, explains
//     the plateau insensitive to occupancy/phase/stores. VGPR 60 -> ~100.

typedef __attribute__((ext_vector_type(8))) _Float16 f16x8;
typedef __attribute__((ext_vector_type(4))) float    f32x4;

#define DDIM 256
#define KCL  100
#define KPAD 112   // 7 * 16
#define NT   7     // column tiles of 16

// Block = 512 threads = 8 waves. Each wave: 32 rows x 112 cols (2x7 MFMA tiles).
// Grid = N/256 blocks. B panel lives in swizzled LDS.
__global__ __launch_bounds__(512, 4) void cluster_q(const float* __restrict__ z,
                                                    const float* __restrict__ cl,
                                                    float* __restrict__ out) {
    __shared__ _Float16 Bs[KPAD * DDIM];   // 57,344 B (reused as store scratch)
    __shared__ float    c2s[KPAD];         // +448 B

    const int tid  = threadIdx.x;
    const int lane = tid & 63;
    const int wv   = tid >> 6;             // 0..7
    const int g    = lane >> 4;            // k-group 0..3
    const int c16  = lane & 15;            // row (A) / col (B) within tile

    const long rowbase = (long)blockIdx.x * 256 + wv * 32;

    // per-lane A pointers: rows (i*16 + c16), k-offset 8*g
    const float* p0 = z + (rowbase + c16) * DDIM + 8 * g;
    const float* p1 = p0 + 16 * DDIM;

    // ---- depth-2 prefetch ring (3 slots, static indexing only) ----
    f32x4 Rlo0[3], Rhi0[3], Rlo1[3], Rhi1[3];

    // issue steps 0,1 BEFORE staging (latency hides under staging loads)
    #pragma unroll
    for (int s = 0; s < 2; ++s) {
        Rlo0[s] = *reinterpret_cast<const f32x4*>(p0 + 32 * s);
        Rhi0[s] = *reinterpret_cast<const f32x4*>(p0 + 32 * s + 4);
        Rlo1[s] = *reinterpret_cast<const f32x4*>(p1 + 32 * s);
        Rhi1[s] = *reinterpret_cast<const f32x4*>(p1 + 32 * s + 4);
    }

    // ---- stage B panel: read cl (f32) -> convert -> swizzled f16 LDS,
    //      and reduce ||c||^2 inline. Swizzle: byte ^= (row&7)<<4.
    #pragma unroll
    for (int j = 0; j < 7; ++j) {
        const int idx = j * 512 + tid;
        const int r   = idx >> 5;          // row 0..111
        const int cw  = idx & 31;          // chunk within row
        f32x4 a = {0.f, 0.f, 0.f, 0.f}, b = {0.f, 0.f, 0.f, 0.f};
        if (r < KCL) {
            const f32x4* src = reinterpret_cast<const f32x4*>(cl) + r * 64 + cw * 2;
            a = src[0];
            b = src[1];
        }
        f16x8 v;
        v[0] = (_Float16)a[0]; v[1] = (_Float16)a[1];
        v[2] = (_Float16)a[2]; v[3] = (_Float16)a[3];
        v[4] = (_Float16)b[0]; v[5] = (_Float16)b[1];
        v[6] = (_Float16)b[2]; v[7] = (_Float16)b[3];
        *reinterpret_cast<f16x8*>(reinterpret_cast<char*>(Bs)
            + r * 512 + ((cw * 16) ^ ((r & 7) << 4))) = v;

        float ss = a[0]*a[0] + a[1]*a[1] + a[2]*a[2] + a[3]*a[3]
                 + b[0]*b[0] + b[1]*b[1] + b[2]*b[2] + b[3]*b[3];
        ss += __shfl_xor(ss, 1);
        ss += __shfl_xor(ss, 2);
        ss += __shfl_xor(ss, 4);
        ss += __shfl_xor(ss, 8);
        ss += __shfl_xor(ss, 16);          // row sum within each 32-lane half
        if ((lane & 31) == 0) c2s[r] = ss;
    }
    __syncthreads();

    f32x4 acc[2][NT];
    #pragma unroll
    for (int i = 0; i < 2; ++i)
        #pragma unroll
        for (int t = 0; t < NT; ++t)
            acc[i][t] = f32x4{0.f, 0.f, 0.f, 0.f};

    float zsq[2] = {0.f, 0.f};

    // per-lane swizzled B row bases
    const int rx = (c16 & 7) << 4;
    const char* bbase = reinterpret_cast<const char*>(Bs) + c16 * 512;

    // K loop: 8 steps of 32, FULLY UNROLLED, distance-2 prefetch ring.
    // A and B use identical (group,reg)->k indexing -> HW k-slot convention
    // cancels; only the C/D layout (epilogue) is load-bearing.
    #pragma unroll
    for (int s = 0; s < 8; ++s) {
        if (s + 2 < 8) {
            const int d = (s + 2) % 3;
            const int kn = 32 * (s + 2);
            Rlo0[d] = *reinterpret_cast<const f32x4*>(p0 + kn);
            Rhi0[d] = *reinterpret_cast<const f32x4*>(p0 + kn + 4);
            Rlo1[d] = *reinterpret_cast<const f32x4*>(p1 + kn);
            Rhi1[d] = *reinterpret_cast<const f32x4*>(p1 + kn + 4);
        }
        const int c = s % 3;
        const f32x4 lo0 = Rlo0[c], hi0 = Rhi0[c];
        const f32x4 lo1 = Rlo1[c], hi1 = Rhi1[c];

        zsq[0] += lo0[0]*lo0[0] + lo0[1]*lo0[1] + lo0[2]*lo0[2] + lo0[3]*lo0[3]
                + hi0[0]*hi0[0] + hi0[1]*hi0[1] + hi0[2]*hi0[2] + hi0[3]*hi0[3];
        zsq[1] += lo1[0]*lo1[0] + lo1[1]*lo1[1] + lo1[2]*lo1[2] + lo1[3]*lo1[3]
                + hi1[0]*hi1[0] + hi1[1]*hi1[1] + hi1[2]*hi1[2] + hi1[3]*hi1[3];

        f16x8 a0, a1;
        a0[0] = (_Float16)lo0[0]; a0[1] = (_Float16)lo0[1];
        a0[2] = (_Float16)lo0[2]; a0[3] = (_Float16)lo0[3];
        a0[4] = (_Float16)hi0[0]; a0[5] = (_Float16)hi0[1];
        a0[6] = (_Float16)hi0[2]; a0[7] = (_Float16)hi0[3];
        a1[0] = (_Float16)lo1[0]; a1[1] = (_Float16)lo1[1];
        a1[2] = (_Float16)lo1[2]; a1[3] = (_Float16)lo1[3];
        a1[4] = (_Float16)hi1[0]; a1[5] = (_Float16)hi1[1];
        a1[6] = (_Float16)hi1[2]; a1[7] = (_Float16)hi1[3];

        const int sb = (64 * s + 16 * g) ^ rx;
        #pragma unroll
        for (int t = 0; t < NT; ++t) {
            f16x8 b = *reinterpret_cast<const f16x8*>(bbase + t * 16 * 512 + sb);
            acc[0][t] = __builtin_amdgcn_mfma_f32_16x16x32_f16(a0, b, acc[0][t], 0, 0, 0);
            acc[1][t] = __builtin_amdgcn_mfma_f32_16x16x32_f16(a1, b, acc[1][t], 0, 0, 0);
        }
    }

    // ||z_row||^2: sum the 4 k-groups (lanes differing in bits 4..5)
    #pragma unroll
    for (int i = 0; i < 2; ++i) {
        zsq[i] += __shfl_xor(zsq[i], 16);
        zsq[i] += __shfl_xor(zsq[i], 32);
    }
    // now lane l holds z2 of row (l & 15) (plus i*16)

    float c2v[NT];
    #pragma unroll
    for (int t = 0; t < NT; ++t) c2v[t] = c2s[t * 16 + c16];

    // all waves done reading the B panel -> Bs becomes store scratch
    __syncthreads();

    // per-wave scratch: 16 rows x 100 f32 = 6400 B (8 waves x 6400 = 51,200 B)
    float* sc = reinterpret_cast<float*>(reinterpret_cast<char*>(Bs) + wv * 6400);

    // Epilogue. C/D layout (verified, guide §3): col = lane&15, row = g*4 + reg.
    #pragma unroll
    for (int i = 0; i < 2; ++i) {
        #pragma unroll
        for (int j = 0; j < 4; ++j) {
            const int r = 4 * g + j;                 // row within 16-tile
            const float z2 = __shfl(zsq[i], r);      // lane r holds row r's norm
            float qv[NT];
            float rs = 0.f;
            #pragma unroll
            for (int t = 0; t < NT; ++t) {
                const float dot = acc[i][t][j];
                const float d2 = fmaxf(z2 + c2v[t] - 2.f * dot, 0.f);
                const float q = __builtin_amdgcn_rcpf(1.f + d2);
                qv[t] = q;
                if (t < 6 || c16 < 4) rs += q;       // mask padded cols 100..111
            }
            // row sum across the 16 lanes of this group (cols)
            rs += __shfl_xor(rs, 1);
            rs += __shfl_xor(rs, 2);
            rs += __shfl_xor(rs, 4);
            rs += __shfl_xor(rs, 8);
            const float rinv = __builtin_amdgcn_rcpf(rs);

            // scatter into wave-local LDS tile (max 2-way bank alias = free)
            #pragma unroll
            for (int t = 0; t < NT; ++t) {
                const int col = t * 16 + c16;
                if (col < KCL) sc[r * KCL + col] = qv[t] * rinv;
            }
        }
        // wave-internal readback (lgkmcnt ordering; no barrier needed):
        // 16 rows x 400 B = 1600 floats; 1KB contiguous per store instruction.
        const long gbase = (rowbase + i * 16) * (long)KCL;
        #pragma unroll
        for (int c = 0; c < 7; ++c) {
            const int off = c * 256 + lane * 4;      // float index
            if (off < 1600) {
                f32x4 v = *reinterpret_cast<const f32x4*>(sc + off);
                *reinterpret_cast<f32x4*>(out + gbase + off) = v;
            }
        }
    }
}

// ---------------- launcher ---------------------------------------------------
extern "C" void kernel_launch(void* const* d_in, const int* in_sizes, int n_in,
                              void* d_out, int out_size, void* d_ws, size_t ws_size,
                              hipStream_t stream) {
    const float* z  = (const float*)d_in[0];
    const float* cl = (const float*)d_in[1];
    float* out = (float*)d_out;

    const int N = in_sizes[0] / DDIM;   // 131072

    cluster_q<<<N / 256, 512, 0, stream>>>(z, cl, out);
}

// Round 10
// 37.942 us; speedup vs baseline: 1.1030x; 1.1030x over previous
//
#include <hip/hip_runtime.h>

// Clustering layer: q[n,k] = t-dist kernel of ||z_n - c_k||^2, row-normalized.
// N=131072, K=100 (pad->112), D=256. f32 in/out; f16 MFMA for the dot products.
//
// R9: sector-dense A loads. R8 depth-2 reverted (regressed). Old pattern:
//     lane g read 16B at byte 32g -> each load instr touched 32 half-filled
//     64B sectors (2x request amplification on the whole z stream). New k-map:
//     lane g holds k {4g..4g+4} u {16+4g..16+4g+4}; lo reads [0,64) hi [64,128)
//     per row = fully dense sectors. B panel staged with matching k-permutation
//     (source offsets only; LDS bytes/swizzle/K-loop reads unchanged) -> A,B
//     keep identical (g,slot)->k maps, dot product invariant.

typedef __attribute__((ext_vector_type(8))) _Float16 f16x8;
typedef __attribute__((ext_vector_type(4))) float    f32x4;

#define DDIM 256
#define KCL  100
#define KPAD 112   // 7 * 16
#define NT   7     // column tiles of 16

// Block = 512 threads = 8 waves. Each wave: 32 rows x 112 cols (2x7 MFMA tiles).
// Grid = N/256 blocks. B panel lives in swizzled LDS.
__global__ __launch_bounds__(512, 4) void cluster_q(const float* __restrict__ z,
                                                    const float* __restrict__ cl,
                                                    float* __restrict__ out) {
    __shared__ _Float16 Bs[KPAD * DDIM];   // 57,344 B (reused as store scratch)
    __shared__ float    c2s[KPAD];         // +448 B

    const int tid  = threadIdx.x;
    const int lane = tid & 63;
    const int wv   = tid >> 6;             // 0..7
    const int g    = lane >> 4;            // k-group 0..3
    const int c16  = lane & 15;            // row (A) / col (B) within tile

    const long rowbase = (long)blockIdx.x * 256 + wv * 32;

    // per-lane A pointers: rows (i*16 + c16). Sector-dense k-map:
    // lo = floats [4g, 4g+4)  -> byte 16g  (4 g-lanes cover [0,64) contiguous)
    // hi = floats [16+4g, ..) -> byte 64+16g (cover [64,128))
    const float* p0 = z + (rowbase + c16) * DDIM + 4 * g;
    const float* p1 = p0 + 16 * DDIM;

    // ---- issue step-0 A prefetch FIRST (latency hides under staging) ----
    f32x4 lo0 = *reinterpret_cast<const f32x4*>(p0);
    f32x4 hi0 = *reinterpret_cast<const f32x4*>(p0 + 16);
    f32x4 lo1 = *reinterpret_cast<const f32x4*>(p1);
    f32x4 hi1 = *reinterpret_cast<const f32x4*>(p1 + 16);

    // ---- stage B panel: read cl (f32) -> convert -> swizzled f16 LDS with
    //      the matching k-permutation: chunk cw (step=cw>>2, gg=cw&3) holds
    //      orig floats {32*step+4*gg ..+4} u {32*step+16+4*gg ..+4}.
    //      ||c||^2 reduced inline. Swizzle: byte ^= (row&7)<<4.
    #pragma unroll
    for (int j = 0; j < 7; ++j) {
        const int idx = j * 512 + tid;
        const int r   = idx >> 5;          // row 0..111
        const int cw  = idx & 31;          // chunk within row
        const int offA = 32 * (cw >> 2) + 4 * (cw & 3);
        f32x4 a = {0.f, 0.f, 0.f, 0.f}, b = {0.f, 0.f, 0.f, 0.f};
        if (r < KCL) {
            const float* base = cl + r * DDIM;
            a = *reinterpret_cast<const f32x4*>(base + offA);
            b = *reinterpret_cast<const f32x4*>(base + offA + 16);
        }
        f16x8 v;
        v[0] = (_Float16)a[0]; v[1] = (_Float16)a[1];
        v[2] = (_Float16)a[2]; v[3] = (_Float16)a[3];
        v[4] = (_Float16)b[0]; v[5] = (_Float16)b[1];
        v[6] = (_Float16)b[2]; v[7] = (_Float16)b[3];
        *reinterpret_cast<f16x8*>(reinterpret_cast<char*>(Bs)
            + r * 512 + ((cw * 16) ^ ((r & 7) << 4))) = v;

        float ss = a[0]*a[0] + a[1]*a[1] + a[2]*a[2] + a[3]*a[3]
                 + b[0]*b[0] + b[1]*b[1] + b[2]*b[2] + b[3]*b[3];
        ss += __shfl_xor(ss, 1);
        ss += __shfl_xor(ss, 2);
        ss += __shfl_xor(ss, 4);
        ss += __shfl_xor(ss, 8);
        ss += __shfl_xor(ss, 16);          // row sum within each 32-lane half
        if ((lane & 31) == 0) c2s[r] = ss;
    }
    __syncthreads();

    f32x4 acc[2][NT];
    #pragma unroll
    for (int i = 0; i < 2; ++i)
        #pragma unroll
        for (int t = 0; t < NT; ++t)
            acc[i][t] = f32x4{0.f, 0.f, 0.f, 0.f};

    float zsq[2] = {0.f, 0.f};

    // per-lane swizzled B row bases
    const int rx = (c16 & 7) << 4;
    const char* bbase = reinterpret_cast<const char*>(Bs) + c16 * 512;

    // K loop: 8 steps of 32. A from global (depth-1 prefetch), B from LDS.
    // A and B use identical (g,slot)->k maps (sector-dense variant) -> HW
    // k-slot convention cancels; only the C/D layout (epilogue) matters.
    #pragma unroll 1
    for (int s = 0; s < 8; ++s) {
        const int kn = (s < 7) ? 32 * (s + 1) : 0;   // next-step prefetch
        f32x4 nlo0 = *reinterpret_cast<const f32x4*>(p0 + kn);
        f32x4 nhi0 = *reinterpret_cast<const f32x4*>(p0 + kn + 16);
        f32x4 nlo1 = *reinterpret_cast<const f32x4*>(p1 + kn);
        f32x4 nhi1 = *reinterpret_cast<const f32x4*>(p1 + kn + 16);

        zsq[0] += lo0[0]*lo0[0] + lo0[1]*lo0[1] + lo0[2]*lo0[2] + lo0[3]*lo0[3]
                + hi0[0]*hi0[0] + hi0[1]*hi0[1] + hi0[2]*hi0[2] + hi0[3]*hi0[3];
        zsq[1] += lo1[0]*lo1[0] + lo1[1]*lo1[1] + lo1[2]*lo1[2] + lo1[3]*lo1[3]
                + hi1[0]*hi1[0] + hi1[1]*hi1[1] + hi1[2]*hi1[2] + hi1[3]*hi1[3];

        f16x8 a0, a1;
        a0[0] = (_Float16)lo0[0]; a0[1] = (_Float16)lo0[1];
        a0[2] = (_Float16)lo0[2]; a0[3] = (_Float16)lo0[3];
        a0[4] = (_Float16)hi0[0]; a0[5] = (_Float16)hi0[1];
        a0[6] = (_Float16)hi0[2]; a0[7] = (_Float16)hi0[3];
        a1[0] = (_Float16)lo1[0]; a1[1] = (_Float16)lo1[1];
        a1[2] = (_Float16)lo1[2]; a1[3] = (_Float16)lo1[3];
        a1[4] = (_Float16)hi1[0]; a1[5] = (_Float16)hi1[1];
        a1[6] = (_Float16)hi1[2]; a1[7] = (_Float16)hi1[3];

        const int sb = (64 * s + 16 * g) ^ rx;
        #pragma unroll
        for (int t = 0; t < NT; ++t) {
            f16x8 b = *reinterpret_cast<const f16x8*>(bbase + t * 16 * 512 + sb);
            acc[0][t] = __builtin_amdgcn_mfma_f32_16x16x32_f16(a0, b, acc[0][t], 0, 0, 0);
            acc[1][t] = __builtin_amdgcn_mfma_f32_16x16x32_f16(a1, b, acc[1][t], 0, 0, 0);
        }

        lo0 = nlo0; hi0 = nhi0; lo1 = nlo1; hi1 = nhi1;
    }

    // ||z_row||^2: per-lane k-sets {4g..4g+4}u{16+4g..} per step; union over
    // the 4 g-lanes = full k range. Sum groups (lanes differing in bits 4..5).
    #pragma unroll
    for (int i = 0; i < 2; ++i) {
        zsq[i] += __shfl_xor(zsq[i], 16);
        zsq[i] += __shfl_xor(zsq[i], 32);
    }
    // now lane l holds z2 of row (l & 15) (plus i*16)

    float c2v[NT];
    #pragma unroll
    for (int t = 0; t < NT; ++t) c2v[t] = c2s[t * 16 + c16];

    // all waves done reading the B panel -> Bs becomes store scratch
    __syncthreads();

    // per-wave scratch: 16 rows x 100 f32 = 6400 B (8 waves x 6400 = 51,200 B)
    float* sc = reinterpret_cast<float*>(reinterpret_cast<char*>(Bs) + wv * 6400);

    // Epilogue. C/D layout (verified, guide §3): col = lane&15, row = g*4 + reg.
    #pragma unroll
    for (int i = 0; i < 2; ++i) {
        #pragma unroll
        for (int j = 0; j < 4; ++j) {
            const int r = 4 * g + j;                 // row within 16-tile
            const float z2 = __shfl(zsq[i], r);      // lane r holds row r's norm
            float qv[NT];
            float rs = 0.f;
            #pragma unroll
            for (int t = 0; t < NT; ++t) {
                const float dot = acc[i][t][j];
                const float d2 = fmaxf(z2 + c2v[t] - 2.f * dot, 0.f);
                const float q = __builtin_amdgcn_rcpf(1.f + d2);
                qv[t] = q;
                if (t < 6 || c16 < 4) rs += q;       // mask padded cols 100..111
            }
            // row sum across the 16 lanes of this group (cols)
            rs += __shfl_xor(rs, 1);
            rs += __shfl_xor(rs, 2);
            rs += __shfl_xor(rs, 4);
            rs += __shfl_xor(rs, 8);
            const float rinv = __builtin_amdgcn_rcpf(rs);

            // scatter into wave-local LDS tile (max 2-way bank alias = free)
            #pragma unroll
            for (int t = 0; t < NT; ++t) {
                const int col = t * 16 + c16;
                if (col < KCL) sc[r * KCL + col] = qv[t] * rinv;
            }
        }
        // wave-internal readback (lgkmcnt ordering; no barrier needed):
        // 16 rows x 400 B = 1600 floats; 1KB contiguous per store instruction.
        const long gbase = (rowbase + i * 16) * (long)KCL;
        #pragma unroll
        for (int c = 0; c < 7; ++c) {
            const int off = c * 256 + lane * 4;      // float index
            if (off < 1600) {
                f32x4 v = *reinterpret_cast<const f32x4*>(sc + off);
                *reinterpret_cast<f32x4*>(out + gbase + off) = v;
            }
        }
    }
}

// ---------------- launcher ---------------------------------------------------
extern "C" void kernel_launch(void* const* d_in, const int* in_sizes, int n_in,
                              void* d_out, int out_size, void* d_ws, size_t ws_size,
                              hipStream_t stream) {
    const float* z  = (const float*)d_in[0];
    const float* cl = (const float*)d_in[1];
    float* out = (float*)d_out;

    const int N = in_sizes[0] / DDIM;   // 131072

    cluster_q<<<N / 256, 512, 0, stream>>>(z, cl, out);
}